// Round 1
// baseline (192.077 us; speedup 1.0000x reference)
//
#include <hip/hip_runtime.h>
#include <math.h>

#define NQ    8192
#define NPTS  32768
#define KNN   64
#define CAP   256            // per-query candidate capacity (4 regs/lane select)
#define G     32             // grid cells per dim
#define NCELLS (G*G*G)
#define GLO   (-4.8f)
#define GINV  (G / 9.6f)     // 1/cell = 1/0.3

// ---- order-preserving float<->uint key ----
__device__ __forceinline__ unsigned key_of(float f) {
  unsigned u = __float_as_uint(f);
  return (u & 0x80000000u) ? ~u : (u | 0x80000000u);
}
__device__ __forceinline__ float val_of(unsigned k) {
  unsigned u = (k & 0x80000000u) ? (k & 0x7fffffffu) : ~k;
  return __uint_as_float(u);
}
__device__ __forceinline__ int mbcnt64(unsigned long long m) {
  return __builtin_amdgcn_mbcnt_hi((unsigned)(m >> 32),
         __builtin_amdgcn_mbcnt_lo((unsigned)m, 0));
}
__device__ __forceinline__ float rflf(float x) {
  return __int_as_float(__builtin_amdgcn_readfirstlane(__float_as_int(x)));
}
__device__ __forceinline__ int rfli(int x) { return __builtin_amdgcn_readfirstlane(x); }

__device__ __forceinline__ float norm_cdf(float x) { return 0.5f * erfcf(-x * 0.70710678f); }
// Mass of standard 3D gaussian inside ball radius r centered at distance mu.
__device__ __forceinline__ float ball_mass(float mu, float r) {
  float a = r - mu, b = r + mu;
  float e = __expf(-0.5f * b * b) - __expf(-0.5f * a * a);
  return e / (mu * 2.50662827f) + norm_cdf(a) - norm_cdf(-mu) + norm_cdf(b) - norm_cdf(mu);
}

__device__ __forceinline__ int cidx(float v) {
  int i = (int)floorf((v - GLO) * GINV);
  return min(max(i, 0), G - 1);
}

// ================= preprocessing =================

__global__ __launch_bounds__(1024) void zero_kernel(int* __restrict__ cnt) {
  cnt[blockIdx.x * 1024 + threadIdx.x] = 0;
}

__global__ __launch_bounds__(256) void hist_tau_kernel(
    const float* __restrict__ pos, const float* __restrict__ qpos,
    int* __restrict__ cnt, float* __restrict__ tau) {
  const int gid = blockIdx.x * 256 + threadIdx.x;          // 32768 threads
  const float x = pos[gid * 3 + 0], y = pos[gid * 3 + 1], z = pos[gid * 3 + 2];
  const int c = (cidx(z) * G + cidx(y)) * G + cidx(x);
  atomicAdd(&cnt[c], 1);
  if (gid < NQ) {
    const float qx = qpos[gid * 3 + 0], qy = qpos[gid * 3 + 1], qz = qpos[gid * 3 + 2];
    const float b = qx * qx + qy * qy + qz * qz;
    const float mu = fmaxf(sqrtf(b), 0.05f);
    const float target = 110.0f / 32768.0f;   // E[cand]=110: P(<64) ~ 5e-6/query
    float lo = 0.f, hi = mu + 8.f;
    for (int i = 0; i < 16; ++i) {
      float r = 0.5f * (lo + hi);
      if (ball_mass(mu, r) < target) lo = r; else hi = r;
    }
    tau[gid] = hi * hi;
  }
}

__global__ __launch_bounds__(1024) void prefix_kernel(
    int* __restrict__ cnt, int* __restrict__ start) {
  __shared__ int sSum[1024];
  const int t = threadIdx.x;
  const int base = t * 32;
  int local[32];
  int s = 0;
  #pragma unroll
  for (int j = 0; j < 32; ++j) { local[j] = s; s += cnt[base + j]; }
  sSum[t] = s;
  __syncthreads();
  for (int off = 1; off < 1024; off <<= 1) {
    int v = (t >= off) ? sSum[t - off] : 0;
    __syncthreads();
    sSum[t] += v;
    __syncthreads();
  }
  const int excl = (t == 0) ? 0 : sSum[t - 1];
  #pragma unroll
  for (int j = 0; j < 32; ++j) {
    const int v = excl + local[j];
    start[base + j] = v;
    cnt[base + j] = v;      // becomes the scatter cursor
  }
  if (t == 1023) start[NCELLS] = excl + s;   // = NPTS
}

__global__ __launch_bounds__(256) void scatter_kernel(
    const float* __restrict__ pos, int* __restrict__ cursor, float4* __restrict__ pts) {
  const int gid = blockIdx.x * 256 + threadIdx.x;
  const float x = pos[gid * 3 + 0], y = pos[gid * 3 + 1], z = pos[gid * 3 + 2];
  const int c = (cidx(z) * G + cidx(y)) * G + cidx(x);
  const int slot = atomicAdd(&cursor[c], 1);
  pts[slot] = make_float4(x, y, z, __int_as_float(gid));
}

// ================= main: one wave per query =================

__global__ __launch_bounds__(256, 8) void knn_main(
    const float* __restrict__ qpos, const float* __restrict__ feat,
    const int* __restrict__ cellStart, const float4* __restrict__ pts,
    const float* __restrict__ tauArr, float* __restrict__ out) {

  __shared__ uint2 sCand[4][CAP];   // per-wave candidate buffer (key, point idx)
  __shared__ uint2 sSel[4][KNN];    // (idx, weight bits)

  const int tid = threadIdx.x, lane = tid & 63, wv = tid >> 6;
  const int gq = blockIdx.x * 4 + wv;

  const float qx = rflf(qpos[gq * 3 + 0]);
  const float qy = rflf(qpos[gq * 3 + 1]);
  const float qz = rflf(qpos[gq * 3 + 2]);
  const float bq = qx * qx + qy * qy + qz * qz;
  const float nx = -2.f * qx, ny = -2.f * qy, nz = -2.f * qz;
  float r2 = rflf(tauArr[gq]);
  float tlo = 0.f, thi = -1.f;
  int cnt = 0;

  // candidate scan over grid cells intersecting the ball (usually 1 attempt)
  for (int attempt = 0; attempt < 12; ++attempt) {
    const float r = sqrtf(r2);
    const float tq = r2 - bq;        // compare d' = |p|^2 - 2 q.p against tau - |q|^2
    const int ix0 = cidx(qx - r), ix1 = cidx(qx + r);
    const int iy0 = cidx(qy - r), iy1 = cidx(qy + r);
    const int iz0 = cidx(qz - r), iz1 = cidx(qz + r);
    cnt = 0;
    for (int iz = iz0; iz <= iz1; ++iz) {
      for (int iy = iy0; iy <= iy1; ++iy) {
        const int rb = (iz * G + iy) * G;
        const int s = rfli(cellStart[rb + ix0]);
        const int e = rfli(cellStart[rb + ix1 + 1]);   // x-range is contiguous
        for (int b = s; b < e; b += 64) {
          const int o = b + lane;
          const float4 P = pts[o];                     // padded tail: garbage is masked below
          const float n = P.x * P.x + P.y * P.y + P.z * P.z;
          const float d = fmaf(P.z, nz, fmaf(P.y, ny, fmaf(P.x, nx, n)));
          const bool h = (o < e) && (d < tq);
          const unsigned long long m = __ballot(h);
          if (m) {
            const int p = cnt + mbcnt64(m);
            if (h && p < CAP)
              sCand[wv][p] = make_uint2(key_of(d + bq), __float_as_uint(P.w));
            cnt += (int)__popcll(m);
          }
        }
      }
    }
    if (cnt >= KNN && cnt <= CAP) break;
    if (cnt < KNN) { tlo = r2; r2 = (thi < 0.f) ? r2 * 3.f : 0.5f * (r2 + thi); }
    else           { thi = r2; r2 = 0.5f * (tlo + r2); }
  }

  // exact top-64 select within the wave (no barriers: wave-private LDS)
  {
    const int mm = min(cnt, CAP);
    unsigned k[4], id[4];
    #pragma unroll
    for (int s = 0; s < 4; ++s) {
      const int g2 = s * 64 + lane;
      uint2 kv = make_uint2(0xFFFFFFFFu, 0u);
      if (g2 < mm) kv = sCand[wv][g2];
      k[s] = kv.x; id[s] = kv.y;
    }
    unsigned blo = 0u, bhi = 0xFFFFFFFFu;   // bisect exact 64th-smallest key
    for (int it = 0; it < 32; ++it) {
      const unsigned mid = blo + ((bhi - blo) >> 1);
      const int c = (int)(__popcll(__ballot(k[0] <= mid)) + __popcll(__ballot(k[1] <= mid)) +
                          __popcll(__ballot(k[2] <= mid)) + __popcll(__ballot(k[3] <= mid)));
      if (c >= KNN) bhi = mid; else blo = mid + 1;
    }
    const unsigned K = blo;

    int fill = 0;
    #pragma unroll
    for (int s = 0; s < 4; ++s) {
      const bool lt = k[s] < K;
      const unsigned long long msk = __ballot(lt);
      if (msk) {
        const int p = fill + mbcnt64(msk);
        if (lt) { const float dv = val_of(k[s]);
                  const float w_ = 1.f / (sqrtf(fmaxf(dv, 1e-12f)) + 1e-5f);
                  sSel[wv][p] = make_uint2(id[s], __float_as_uint(w_)); }
        fill += (int)__popcll(msk);
      }
    }
    #pragma unroll
    for (int s = 0; s < 4; ++s) {          // ties at K fill remaining slots
      const bool eq = (k[s] == K);
      const unsigned long long msk = __ballot(eq);
      if (msk) {
        const int p = fill + mbcnt64(msk);
        if (eq && p < KNN) { const float dv = val_of(k[s]);
                             const float w_ = 1.f / (sqrtf(fmaxf(dv, 1e-12f)) + 1e-5f);
                             sSel[wv][p] = make_uint2(id[s], __float_as_uint(w_)); }
        fill += (int)__popcll(msk);
      }
    }
  }

  // weighted feature gather (wave-private, no barrier)
  {
    float ax = 0.f, ay = 0.f;
    #pragma unroll 8
    for (int j = 0; j < KNN; ++j) {
      const uint2 pr = sSel[wv][j];          // broadcast LDS read
      const float w = __uint_as_float(pr.y);
      const float2 f2 = *(const float2*)(feat + ((size_t)pr.x << 7) + (lane << 1));
      ax = fmaf(w, f2.x, ax);
      ay = fmaf(w, f2.y, ay);
    }
    *(float2*)(out + ((size_t)gq << 7) + (lane << 1)) = make_float2(ax, ay);
  }
}

extern "C" void kernel_launch(void* const* d_in, const int* in_sizes, int n_in,
                              void* d_out, int out_size, void* d_ws, size_t ws_size,
                              hipStream_t stream) {
  const float* qpos = (const float*)d_in[0];   // [8192,3]
  const float* feat = (const float*)d_in[1];   // [32768,128]
  const float* pos  = (const float*)d_in[2];   // [32768,3]
  float* out = (float*)d_out;                  // [8192,128]

  char* ws = (char*)d_ws;
  int*    cnt   = (int*)(ws);                              // 32768 ints (hist, then cursor)
  int*    start = (int*)(ws + (128 << 10));                // 32769 ints
  float4* pts   = (float4*)(ws + (256 << 10) + 16);        // (32768+64) float4, 16B aligned
  float*  tau   = (float*)(ws + (256 << 10) + 16 + (size_t)(NPTS + 64) * 16);  // 8192 floats

  zero_kernel   <<<dim3(NCELLS / 1024), dim3(1024), 0, stream>>>(cnt);
  hist_tau_kernel<<<dim3(NPTS / 256),   dim3(256),  0, stream>>>(pos, qpos, cnt, tau);
  prefix_kernel <<<dim3(1),             dim3(1024), 0, stream>>>(cnt, start);
  scatter_kernel<<<dim3(NPTS / 256),    dim3(256),  0, stream>>>(pos, cnt, pts);
  knn_main      <<<dim3(NQ / 4),        dim3(256),  0, stream>>>(qpos, feat, start, pts, tau, out);
}

// Round 2
// 133.975 us; speedup vs baseline: 1.4337x; 1.4337x over previous
//
#include <hip/hip_runtime.h>
#include <math.h>

#define NQ    8192
#define NPTS  32768
#define KNN   64
#define CAP   256            // per-query candidate capacity (4 regs/lane select)
#define G     32             // grid cells per dim
#define NCELLS (G*G*G)
#define GLO   (-4.8f)
#define GINV  (G / 9.6f)     // 1/cell = 1/0.3
#define NBLK  2048           // main grid: 4 queries (waves) per block

// ---- order-preserving float<->uint key ----
__device__ __forceinline__ unsigned key_of(float f) {
  unsigned u = __float_as_uint(f);
  return (u & 0x80000000u) ? ~u : (u | 0x80000000u);
}
__device__ __forceinline__ float val_of(unsigned k) {
  unsigned u = (k & 0x80000000u) ? (k & 0x7fffffffu) : ~k;
  return __uint_as_float(u);
}
__device__ __forceinline__ int mbcnt64(unsigned long long m) {
  return __builtin_amdgcn_mbcnt_hi((unsigned)(m >> 32),
         __builtin_amdgcn_mbcnt_lo((unsigned)m, 0));
}
__device__ __forceinline__ float rflf(float x) {
  return __int_as_float(__builtin_amdgcn_readfirstlane(__float_as_int(x)));
}
__device__ __forceinline__ int rfli(int x) { return __builtin_amdgcn_readfirstlane(x); }

__device__ __forceinline__ float norm_cdf(float x) { return 0.5f * erfcf(-x * 0.70710678f); }
// Mass of standard 3D gaussian inside ball radius r centered at distance mu.
__device__ __forceinline__ float ball_mass(float mu, float r) {
  float a = r - mu, b = r + mu;
  float e = __expf(-0.5f * b * b) - __expf(-0.5f * a * a);
  return e / (mu * 2.50662827f) + norm_cdf(a) - norm_cdf(-mu) + norm_cdf(b) - norm_cdf(mu);
}

__device__ __forceinline__ int cidx(float v) {
  int i = (int)floorf((v - GLO) * GINV);
  return min(max(i, 0), G - 1);
}

// ================= preprocessing =================
// counters zeroed by hipMemsetAsync before this kernel

__global__ __launch_bounds__(256) void hist_tau_kernel(
    const float* __restrict__ pos, const float* __restrict__ qpos,
    int* __restrict__ pcnt, int* __restrict__ qcnt, float* __restrict__ tau) {
  const int gid = blockIdx.x * 256 + threadIdx.x;          // 32768 threads
  const float x = pos[gid * 3 + 0], y = pos[gid * 3 + 1], z = pos[gid * 3 + 2];
  atomicAdd(&pcnt[(cidx(z) * G + cidx(y)) * G + cidx(x)], 1);
  if (gid < NQ) {
    const float qx = qpos[gid * 3 + 0], qy = qpos[gid * 3 + 1], qz = qpos[gid * 3 + 2];
    atomicAdd(&qcnt[(cidx(qz) * G + cidx(qy)) * G + cidx(qx)], 1);
    const float b = qx * qx + qy * qy + qz * qz;
    const float mu = fmaxf(sqrtf(b), 0.05f);
    const float target = 110.0f / 32768.0f;   // E[cand]=110: P(<64) ~ 5e-6/query
    float lo = 0.f, hi = mu + 8.f;
    for (int i = 0; i < 16; ++i) {
      float r = 0.5f * (lo + hi);
      if (ball_mass(mu, r) < target) lo = r; else hi = r;
    }
    tau[gid] = hi * hi;
  }
}

// block 0: point histogram -> cellStart + cursor; block 1: query histogram -> cursor
__global__ __launch_bounds__(1024) void prefix_kernel(
    int* __restrict__ pcnt, int* __restrict__ start, int* __restrict__ qcnt) {
  __shared__ int sSum[1024];
  const int t = threadIdx.x;
  int* src = (blockIdx.x == 0) ? pcnt : qcnt;
  const int base = t * 32;
  int v[32];
  {
    const int4* cp = (const int4*)(src + base);
    #pragma unroll
    for (int j = 0; j < 8; ++j) { const int4 q = cp[j];
      v[j*4+0]=q.x; v[j*4+1]=q.y; v[j*4+2]=q.z; v[j*4+3]=q.w; }
  }
  int s = 0;
  #pragma unroll
  for (int j = 0; j < 32; ++j) { const int c = v[j]; v[j] = s; s += c; }
  sSum[t] = s;
  __syncthreads();
  for (int off = 1; off < 1024; off <<= 1) {
    const int u = (t >= off) ? sSum[t - off] : 0;
    __syncthreads();
    sSum[t] += u;
    __syncthreads();
  }
  const int excl = (t == 0) ? 0 : sSum[t - 1];
  if (blockIdx.x == 0) {
    #pragma unroll
    for (int j = 0; j < 8; ++j) {
      const int4 q = make_int4(excl+v[j*4], excl+v[j*4+1], excl+v[j*4+2], excl+v[j*4+3]);
      ((int4*)(start + base))[j] = q;   // cellStart (persistent for main)
      ((int4*)(pcnt  + base))[j] = q;   // scatter cursor
    }
    if (t == 1023) start[NCELLS] = NPTS;
  } else {
    #pragma unroll
    for (int j = 0; j < 8; ++j) {
      const int4 q = make_int4(excl+v[j*4], excl+v[j*4+1], excl+v[j*4+2], excl+v[j*4+3]);
      ((int4*)(qcnt + base))[j] = q;    // query scatter cursor
    }
  }
}

__global__ __launch_bounds__(256) void scatter_kernel(
    const float* __restrict__ pos, const float* __restrict__ qpos,
    int* __restrict__ pcur, int* __restrict__ qcur, const float* __restrict__ tau,
    float4* __restrict__ pts, float4* __restrict__ qp, float* __restrict__ qtau) {
  const int gid = blockIdx.x * 256 + threadIdx.x;
  const float x = pos[gid * 3 + 0], y = pos[gid * 3 + 1], z = pos[gid * 3 + 2];
  const int c = (cidx(z) * G + cidx(y)) * G + cidx(x);
  const int slot = atomicAdd(&pcur[c], 1);
  pts[slot] = make_float4(x, y, z, __int_as_float(gid));
  if (gid < NQ) {
    const float a = qpos[gid * 3 + 0], b = qpos[gid * 3 + 1], d = qpos[gid * 3 + 2];
    const int qc = (cidx(d) * G + cidx(b)) * G + cidx(a);
    const int qs = atomicAdd(&qcur[qc], 1);
    qp[qs] = make_float4(a, b, d, __int_as_float(gid));
    qtau[qs] = tau[gid];
  }
}

// ================= main: one wave per (spatially sorted) query =================

__global__ __launch_bounds__(256, 8) void knn_main(
    const float* __restrict__ feat, const int* __restrict__ cellStart,
    const float4* __restrict__ pts, const float4* __restrict__ qp,
    const float* __restrict__ qtau, float* __restrict__ out) {

  __shared__ uint2 sCand[4][CAP];   // per-wave candidate buffer (key, point idx)
  __shared__ uint2 sSel[4][KNN];    // (idx, weight bits)
  __shared__ int   sCum[4][64];     // per-row inclusive prefix of point counts
  __shared__ int   sAdj[4][64];     // per-row (cell start - flat base)

  const int tid = threadIdx.x, lane = tid & 63, wv = tid >> 6;
  // XCD swizzle: 256 consecutive blocks (1024 spatially-adjacent queries) per XCD
  const int bid = blockIdx.x;
  const int swz = (bid & 7) * (NBLK / 8) + (bid >> 3);
  const int sq  = swz * 4 + wv;

  const float4 Q = qp[sq];
  const float qx = rflf(Q.x), qy = rflf(Q.y), qz = rflf(Q.z);
  const int orig = rfli(__float_as_int(Q.w));
  const float bq = qx * qx + qy * qy + qz * qz;
  const float nx = -2.f * qx, ny = -2.f * qy, nz = -2.f * qz;
  float r2 = rflf(qtau[sq]);
  float tlo = 0.f, thi = -1.f;
  int cnt = 0;

  // ---- balanced candidate scan (usually 1 attempt) ----
  for (int attempt = 0; attempt < 12; ++attempt) {
    const float r = sqrtf(r2);
    const float tq = r2 - bq;        // d' = |p|^2 - 2 q.p  vs  tau - |q|^2
    const int ix0 = cidx(qx - r), ix1 = cidx(qx + r);
    const int iy0 = cidx(qy - r), iy1 = cidx(qy + r);
    const int iz0 = cidx(qz - r), iz1 = cidx(qz + r);
    const int nyw  = iy1 - iy0 + 1;
    const int nrow = nyw * (iz1 - iz0 + 1);
    cnt = 0;
    for (int rc = 0; rc < nrow; rc += 64) {
      // lane-parallel row-bound fetch: one latency round covers 64 rows
      const int myrow = rc + lane;
      int s = 0, c = 0;
      if (myrow < nrow) {
        const int dz = myrow / nyw;            // nyw in [1,32]
        const int dy = myrow - dz * nyw;
        const int rb = ((iz0 + dz) * G + (iy0 + dy)) * G;
        s = cellStart[rb + ix0];
        c = cellStart[rb + ix1 + 1] - s;       // x-run is contiguous in sorted pts
      }
      int cum = c;
      #pragma unroll
      for (int off = 1; off < 64; off <<= 1) {
        const int u = __shfl_up(cum, off);
        if (lane >= off) cum += u;
      }
      sCum[wv][lane] = cum;
      sAdj[wv][lane] = s - (cum - c);
      const int Tc = __shfl(cum, 63);
      // flattened point scan: all 64 lanes always busy, empty rows cost nothing
      for (int b = 0; b < Tc; b += 64) {
        const int fi = b + lane;
        const bool have = fi < Tc;
        int ro = 0;
        #pragma unroll
        for (int st = 32; st; st >>= 1) {      // row = #{j: cum[j] <= fi}
          const int nr = ro + st;
          if (nr <= 64 && sCum[wv][nr - 1] <= fi) ro = nr;
        }
        const int pi = have ? fi + sAdj[wv][min(ro, 63)] : 0;
        const float4 P = pts[pi];
        const float n = P.x * P.x + P.y * P.y + P.z * P.z;
        const float d = fmaf(P.z, nz, fmaf(P.y, ny, fmaf(P.x, nx, n)));
        const bool h = have && (d < tq);
        const unsigned long long m = __ballot(h);
        if (m) {
          const int p = cnt + mbcnt64(m);
          if (h && p < CAP)
            sCand[wv][p] = make_uint2(key_of(d + bq), __float_as_uint(P.w));
          cnt += (int)__popcll(m);
        }
      }
    }
    if (cnt >= KNN && cnt <= CAP) break;
    if (cnt < KNN) { tlo = r2; r2 = (thi < 0.f) ? r2 * 3.f : 0.5f * (r2 + thi); }
    else           { thi = r2; r2 = 0.5f * (tlo + r2); }
  }

  // ---- exact top-64 select within the wave ----
  {
    const int mm = min(cnt, CAP);
    unsigned k[4], id[4];
    #pragma unroll
    for (int s = 0; s < 4; ++s) {
      const int g2 = s * 64 + lane;
      uint2 kv = make_uint2(0xFFFFFFFFu, 0u);
      if (g2 < mm) kv = sCand[wv][g2];
      k[s] = kv.x; id[s] = kv.y;
    }
    unsigned blo = 0u, bhi = 0xFFFFFFFFu;   // bisect exact 64th-smallest key
    for (int it = 0; it < 32; ++it) {
      const unsigned mid = blo + ((bhi - blo) >> 1);
      const int c = (int)(__popcll(__ballot(k[0] <= mid)) + __popcll(__ballot(k[1] <= mid)) +
                          __popcll(__ballot(k[2] <= mid)) + __popcll(__ballot(k[3] <= mid)));
      if (c >= KNN) bhi = mid; else blo = mid + 1;
    }
    const unsigned K = blo;

    int fill = 0;
    #pragma unroll
    for (int s = 0; s < 4; ++s) {
      const bool lt = k[s] < K;
      const unsigned long long msk = __ballot(lt);
      if (msk) {
        const int p = fill + mbcnt64(msk);
        if (lt) { const float dv = val_of(k[s]);
                  const float w_ = 1.f / (sqrtf(fmaxf(dv, 1e-12f)) + 1e-5f);
                  sSel[wv][p] = make_uint2(id[s], __float_as_uint(w_)); }
        fill += (int)__popcll(msk);
      }
    }
    #pragma unroll
    for (int s = 0; s < 4; ++s) {          // ties at K fill remaining slots
      const bool eq = (k[s] == K);
      const unsigned long long msk = __ballot(eq);
      if (msk) {
        const int p = fill + mbcnt64(msk);
        if (eq && p < KNN) { const float dv = val_of(k[s]);
                             const float w_ = 1.f / (sqrtf(fmaxf(dv, 1e-12f)) + 1e-5f);
                             sSel[wv][p] = make_uint2(id[s], __float_as_uint(w_)); }
        fill += (int)__popcll(msk);
      }
    }
  }

  // ---- weighted feature gather (wave-private; sorted queries give L1/L2 reuse) ----
  {
    float ax = 0.f, ay = 0.f;
    #pragma unroll 8
    for (int j = 0; j < KNN; ++j) {
      const uint2 pr = sSel[wv][j];          // broadcast LDS read
      const float w = __uint_as_float(pr.y);
      const float2 f2 = *(const float2*)(feat + ((size_t)pr.x << 7) + (lane << 1));
      ax = fmaf(w, f2.x, ax);
      ay = fmaf(w, f2.y, ay);
    }
    *(float2*)(out + ((size_t)orig << 7) + (lane << 1)) = make_float2(ax, ay);
  }
}

extern "C" void kernel_launch(void* const* d_in, const int* in_sizes, int n_in,
                              void* d_out, int out_size, void* d_ws, size_t ws_size,
                              hipStream_t stream) {
  const float* qpos = (const float*)d_in[0];   // [8192,3]
  const float* feat = (const float*)d_in[1];   // [32768,128]
  const float* pos  = (const float*)d_in[2];   // [32768,3]
  float* out = (float*)d_out;                  // [8192,128]

  char* ws = (char*)d_ws;
  int*    pcnt      = (int*)(ws);                      // 128 KB  (hist -> cursor)
  int*    qcnt      = (int*)(ws + (128 << 10));        // 128 KB  (hist -> cursor)
  int*    cellStart = (int*)(ws + (256 << 10));        // 32769 ints
  float*  tau       = (float*)(ws + (392 << 10));      // 32 KB (by orig query idx)
  float4* pts       = (float4*)(ws + (424 << 10));     // 512 KB (sorted points)
  float4* qp        = (float4*)(ws + (936 << 10));     // 128 KB (sorted queries)
  float*  qtau      = (float*)(ws + (1064 << 10));     // 32 KB (sorted tau)

  hipMemsetAsync(ws, 0, 256 << 10, stream);            // zero both histograms
  hist_tau_kernel<<<dim3(NPTS / 256), dim3(256),  0, stream>>>(pos, qpos, pcnt, qcnt, tau);
  prefix_kernel  <<<dim3(2),          dim3(1024), 0, stream>>>(pcnt, cellStart, qcnt);
  scatter_kernel <<<dim3(NPTS / 256), dim3(256),  0, stream>>>(pos, qpos, pcnt, qcnt, tau, pts, qp, qtau);
  knn_main       <<<dim3(NBLK),       dim3(256),  0, stream>>>(feat, cellStart, pts, qp, qtau, out);
}